// Round 11
// baseline (207.494 us; speedup 1.0000x reference)
//
#include <hip/hip_runtime.h>
#include <cstdint>
#include <cstddef>

#define DIM    256
#define BATCH  4096

typedef _Float16 f16x8 __attribute__((ext_vector_type(8)));
typedef _Float16 f16x4 __attribute__((ext_vector_type(4)));
typedef float    f32x4 __attribute__((ext_vector_type(4)));

// ---- ws float-slot offsets (regions overlap across pipeline phases) ----
#define OFF_APK  0u        // 4096x512 halfs [hi|lo] (pack..gemm)
#define OFF_S    0u        // 4096x256 f32 (memset after gemm)
#define OFF_BPK  1048576u  // 4096x512 halfs (pack..gemm)
#define OFF_CNT  1048576u  // 4096 f32 (contiguous with S -> one memset)
#define OFF_U    1052672u  // 64x64x256 f32 (e1..e2)
#define OFF_GX   2101248u
#define OFF_WCNT 2105344u
#define OFF_XN   2109440u
#define OFF_CN   2113536u
#define OFF_MD   2117632u
#define OFF_PV   2121728u
#define OFF_PI   2252800u  // ..2383872 slots = 9.54 MB

// ---- out float offsets ----
#define OUT_BMU  1048576u
#define OUT_MD   1056768u

// ---------------- pack f16 hi/lo + norms + Gx (block 0) ----------------
__global__ __launch_bounds__(256) void packnorm_kernel(
    const float* __restrict__ x, const float* __restrict__ cen,
    const float* __restrict__ lr,
    _Float16* __restrict__ Apk, _Float16* __restrict__ Bpk,
    float* __restrict__ xn, float* __restrict__ cn, float* __restrict__ Gx) {
  int row  = blockIdx.x * 4 + (threadIdx.x >> 6);
  int lane = threadIdx.x & 63;
  bool isx = row < BATCH;
  const float* src = isx ? (x + (size_t)row * DIM)
                         : (cen + (size_t)(row - BATCH) * DIM);
  float4 v = *(const float4*)(src + lane * 4);
  _Float16 h0 = (_Float16)v.x, h1 = (_Float16)v.y,
           h2 = (_Float16)v.z, h3 = (_Float16)v.w;
  _Float16 l0 = (_Float16)(v.x - (float)h0), l1 = (_Float16)(v.y - (float)h1),
           l2 = (_Float16)(v.z - (float)h2), l3 = (_Float16)(v.w - (float)h3);
  _Float16* dst = (isx ? Apk : Bpk) + (size_t)(isx ? row : row - BATCH) * 512;
  *(f16x4*)(dst + lane * 4)       = (f16x4){h0, h1, h2, h3};
  *(f16x4*)(dst + 256 + lane * 4) = (f16x4){l0, l1, l2, l3};
  float s = v.x * v.x + v.y * v.y + v.z * v.z + v.w * v.w;
#pragma unroll
  for (int off = 32; off >= 1; off >>= 1) s += __shfl_xor(s, off);
  if (lane == 0) { if (isx) xn[row] = s; else cn[row - BATCH] = s; }
  if (blockIdx.x == 0) {
    float sg  = 32.f * lr[0];
    float inv = 1.f / (2.f * sg * sg + 1e-5f);
#pragma unroll
    for (int i = 0; i < 16; ++i) {
      int g = i * 256 + threadIdx.x;
      float d = (float)((g >> 6) - (g & 63));
      Gx[g] = expf(-d * d * inv);
    }
  }
}

// ---- FLAT register-direct 3-term f16-split GEMM: no LDS, no barriers in
// ---- main loop. Each wave loads its own fragments from L2-resident Apk/Bpk;
// ---- all k/half offsets fold into load offset immediates. ----
__global__ __launch_bounds__(256, 2) void gemm_argmin_kernel(
    const _Float16* __restrict__ Apk, const _Float16* __restrict__ Bpk,
    const float* __restrict__ cnorm, float* __restrict__ pv, int* __restrict__ pi) {
  __shared__ float cv[256];   // [128][2]
  __shared__ int   ci[256];
  const int tid  = threadIdx.x;
  const int lane = tid & 63, w = tid >> 6;
  const int wr = w >> 1, wc = w & 1;
  const int row0 = blockIdx.y * 128, col0 = blockIdx.x * 128;
  const int t15 = lane & 15, q = lane >> 4;

  // 8 base pointers; everything else (kc*64B, +512B lo-half) folds to imm offsets
  const _Float16* Ab[4];
  const _Float16* Bb[4];
#pragma unroll
  for (int m = 0; m < 4; ++m)
    Ab[m] = Apk + (size_t)(row0 + wr * 64 + m * 16 + t15) * 512 + q * 8;
#pragma unroll
  for (int n = 0; n < 4; ++n)
    Bb[n] = Bpk + (size_t)(col0 + wc * 64 + n * 16 + t15) * 512 + q * 8;

  f32x4 acc[4][4];
#pragma unroll
  for (int m = 0; m < 4; ++m)
#pragma unroll
    for (int n = 0; n < 4; ++n) acc[m][n] = (f32x4){0.f, 0.f, 0.f, 0.f};

#pragma unroll
  for (int kc = 0; kc < 8; ++kc) {
    f16x8 afh[4], afl[4], bfh[4], bfl[4];
#pragma unroll
    for (int m = 0; m < 4; ++m) {
      afh[m] = *(const f16x8*)(Ab[m] + kc * 32);
      afl[m] = *(const f16x8*)(Ab[m] + kc * 32 + 256);
    }
#pragma unroll
    for (int n = 0; n < 4; ++n) {
      bfh[n] = *(const f16x8*)(Bb[n] + kc * 32);
      bfl[n] = *(const f16x8*)(Bb[n] + kc * 32 + 256);
    }
#pragma unroll
    for (int m = 0; m < 4; ++m)
#pragma unroll
      for (int n = 0; n < 4; ++n) {
        acc[m][n] = __builtin_amdgcn_mfma_f32_16x16x32_f16(afh[m], bfh[n], acc[m][n], 0, 0, 0);
        acc[m][n] = __builtin_amdgcn_mfma_f32_16x16x32_f16(afh[m], bfl[n], acc[m][n], 0, 0, 0);
        acc[m][n] = __builtin_amdgcn_mfma_f32_16x16x32_f16(afl[m], bfh[n], acc[m][n], 0, 0, 0);
      }
  }

  // epilogue: v = cnorm[c] - 2*dot; per-row first-min over this 128-col block
  float cnv[4];
#pragma unroll
  for (int n = 0; n < 4; ++n) cnv[n] = cnorm[col0 + wc * 64 + n * 16 + t15];

#pragma unroll
  for (int m = 0; m < 4; ++m) {
#pragma unroll
    for (int reg = 0; reg < 4; ++reg) {
      float bv = 1e30f; int bi = 0x7fffffff;
#pragma unroll
      for (int n = 0; n < 4; ++n) {    // cols ascend with n -> first-min
        float v = cnv[n] - 2.f * acc[m][n][reg];
        if (v < bv) { bv = v; bi = col0 + wc * 64 + n * 16 + t15; }
      }
#pragma unroll
      for (int off = 1; off < 16; off <<= 1) {
        float ov = __shfl_xor(bv, off);
        int   oi = __shfl_xor(bi, off);
        if (ov < bv || (ov == bv && oi < bi)) { bv = ov; bi = oi; }
      }
      if (t15 == 0) {
        int r = wr * 64 + m * 16 + q * 4 + reg;
        cv[r * 2 + wc] = bv;
        ci[r * 2 + wc] = bi;
      }
    }
  }
  __syncthreads();
  if (tid < 128) {
    float v0 = cv[tid * 2];     int i0 = ci[tid * 2];
    float v1 = cv[tid * 2 + 1]; int i1 = ci[tid * 2 + 1];
    if (v1 < v0 || (v1 == v0 && i1 < i0)) { v0 = v1; i0 = i1; }
    pv[(size_t)(row0 + tid) * 32 + blockIdx.x] = v0;
    pi[(size_t)(row0 + tid) * 32 + blockIdx.x] = i0;
  }
}

// ------- finalize: 4 rows/block, wavewide reduce, no LDS, scatter S/cnt -------
__global__ __launch_bounds__(256) void finalize_kernel(
    const float* __restrict__ pv, const int* __restrict__ pi,
    const float* __restrict__ xn, const float* __restrict__ x,
    float* __restrict__ S, float* __restrict__ cnt,
    float* __restrict__ md, float* __restrict__ out) {
  const int w = threadIdx.x >> 6, l = threadIdx.x & 63;
  const int b = blockIdx.x * 4 + w;
  float v = pv[(size_t)b * 32 + (l & 31)];     // both 32-halves load same data
  int idx  = pi[(size_t)b * 32 + (l & 31)];
#pragma unroll
  for (int off = 16; off >= 1; off >>= 1) {
    float ov = __shfl_xor(v, off);
    int   oi = __shfl_xor(idx, off);
    if (ov < v || (ov == v && oi < idx)) { v = ov; idx = oi; }
  }
  if (l == 0) {
    md[b] = sqrtf(fmaxf(xn[b] + v, 0.f));
    out[OUT_BMU + (size_t)b * 2 + 0] = (float)(idx >> 6);
    out[OUT_BMU + (size_t)b * 2 + 1] = (float)(idx & 63);
    atomicAdd(cnt + idx, 1.f);
  }
#pragma unroll
  for (int c = 0; c < 4; ++c)
    atomicAdd(S + (size_t)idx * DIM + c * 64 + l, x[(size_t)b * DIM + c * 64 + l]);
}

// --- e1 (blk 0-255) || wcnt (blk 256-271) || md-reduce (blk 272) ---
__global__ __launch_bounds__(256) void e1_kernel(const float* __restrict__ S,
                                                 const float* __restrict__ Gx,
                                                 const float* __restrict__ cnt,
                                                 const float* __restrict__ md,
                                                 float* __restrict__ U,
                                                 float* __restrict__ Wcnt,
                                                 float* __restrict__ out) {
  __shared__ float smem[12288];        // 48 KiB shared across branches
  const int bid = blockIdx.x, tid = threadIdx.x;
  if (bid < 256) {
    float* Ss = smem;                  // [64 ki][64 dd]
    const int dd = tid & 63, gq = tid >> 6;
    const int kj = bid >> 2, dq = bid & 3;
#pragma unroll 4
    for (int i = 0; i < 16; ++i) {
      int ki = i * 4 + gq;
      Ss[ki * 64 + dd] = S[((size_t)ki * 64 + kj) * 256 + dq * 64 + dd];
    }
    __syncthreads();
    float a[16];
#pragma unroll
    for (int gg = 0; gg < 16; ++gg) a[gg] = 0.f;
    for (int ki = 0; ki < 64; ++ki) {
      float s = Ss[ki * 64 + dd];
#pragma unroll
      for (int gg = 0; gg < 16; ++gg)
        a[gg] += Gx[ki * 64 + gq * 16 + gg] * s;   // wave-uniform -> s_load
    }
#pragma unroll
    for (int gg = 0; gg < 16; ++gg)
      U[((size_t)(gq * 16 + gg) * 64 + kj) * 256 + dq * 64 + dd] = a[gg];
  } else if (bid < 272) {
    float* cs = smem;
    float* gs = smem + 4096;
    float* inner = smem + 8192;
    for (int i = 0; i < 16; i++) { cs[i * 256 + tid] = cnt[i * 256 + tid]; gs[i * 256 + tid] = Gx[i * 256 + tid]; }
    __syncthreads();
    for (int i = 0; i < 16; i++) {
      int idx = i * 256 + tid; int ki = idx >> 6, gj = idx & 63;
      float a = 0.f;
      for (int kj = 0; kj < 64; kj++) a += gs[kj * 64 + gj] * cs[ki * 64 + kj];
      inner[idx] = a;
    }
    __syncthreads();
    const int g = (bid - 256) * 256 + tid, gi = g >> 6, gj = g & 63;
    float a = 0.f;
    for (int ki = 0; ki < 64; ki++) a += gs[gi * 64 + ki] * inner[ki * 64 + gj];
    Wcnt[g] = a;
  } else {
    float s = 0.f;
#pragma unroll
    for (int i = 0; i < 16; i++) s += md[i * 256 + tid];
#pragma unroll
    for (int off = 32; off >= 1; off >>= 1) s += __shfl_xor(s, off);
    if ((tid & 63) == 0) smem[tid >> 6] = s;
    __syncthreads();
    if (tid == 0) out[OUT_MD] = (smem[0] + smem[1] + smem[2] + smem[3]) * (1.f / (float)BATCH);
  }
}

// --- e2 + fused centroid write ; grid (gi,dquad)=256 ---
__global__ __launch_bounds__(256) void e2_kernel(const float* __restrict__ U,
                                                 const float* __restrict__ Gx,
                                                 const float* __restrict__ Wcnt,
                                                 const float* __restrict__ cen,
                                                 const float* __restrict__ lr,
                                                 float* __restrict__ out) {
  __shared__ float Us[4096];           // [64 kj][64 dd]
  const int t = threadIdx.x, dd = t & 63, gq = t >> 6;
  const int gi = blockIdx.x >> 2, dq = blockIdx.x & 3;
#pragma unroll 4
  for (int i = 0; i < 16; ++i) {
    int kj = i * 4 + gq;
    Us[kj * 64 + dd] = U[((size_t)gi * 64 + kj) * 256 + dq * 64 + dd];
  }
  __syncthreads();
  float a[16];
#pragma unroll
  for (int gg = 0; gg < 16; ++gg) a[gg] = 0.f;
  for (int kj = 0; kj < 64; ++kj) {
    float s = Us[kj * 64 + dd];
#pragma unroll
    for (int gg = 0; gg < 16; ++gg)
      a[gg] += Gx[kj * 64 + gq * 16 + gg] * s;
  }
  const float coef = 0.5f * lr[0] / (float)BATCH;
#pragma unroll
  for (int gg = 0; gg < 16; ++gg) {
    int g = gi * 64 + gq * 16 + gg;
    float c = cen[(size_t)g * 256 + dq * 64 + dd];
    out[(size_t)g * 256 + dq * 64 + dd] = c + coef * (a[gg] - Wcnt[g] * c);
  }
}

extern "C" void kernel_launch(void* const* d_in, const int* in_sizes, int n_in,
                              void* d_out, int out_size, void* d_ws, size_t ws_size,
                              hipStream_t stream) {
  const float* x   = (const float*)d_in[0];
  const float* cen = (const float*)d_in[1];
  const float* lr  = (const float*)d_in[4];
  float* out = (float*)d_out;
  float* ws  = (float*)d_ws;

  _Float16* Apk = (_Float16*)(ws + OFF_APK);
  _Float16* Bpk = (_Float16*)(ws + OFF_BPK);
  float* S    = ws + OFF_S;
  float* cnt  = ws + OFF_CNT;
  float* U    = ws + OFF_U;
  float* Gx   = ws + OFF_GX;
  float* Wcnt = ws + OFF_WCNT;
  float* xn   = ws + OFF_XN;
  float* cnw  = ws + OFF_CN;
  float* md   = ws + OFF_MD;
  float* pv   = ws + OFF_PV;
  int*   pi   = (int*)(ws + OFF_PI);

  packnorm_kernel<<<2048, 256, 0, stream>>>(x, cen, lr, Apk, Bpk, xn, cnw, Gx);
  gemm_argmin_kernel<<<dim3(32, 32), 256, 0, stream>>>(Apk, Bpk, cnw, pv, pi);
  hipMemsetAsync(S, 0, (size_t)(1048576 + 4096) * sizeof(float), stream);  // S+cnt
  finalize_kernel<<<1024, 256, 0, stream>>>(pv, pi, xn, x, S, cnt, md, out);
  e1_kernel<<<273, 256, 0, stream>>>(S, Gx, cnt, md, U, Wcnt, out);
  e2_kernel<<<256, 256, 0, stream>>>(U, Gx, Wcnt, cen, lr, out);
}